// Round 1
// baseline (422.340 us; speedup 1.0000x reference)
//
#include <hip/hip_runtime.h>

#define EPSF 1e-6f

typedef _Float16 f16x8 __attribute__((ext_vector_type(8)));
typedef _Float16 f16x4 __attribute__((ext_vector_type(4)));
typedef float    f32x4 __attribute__((ext_vector_type(4)));

#define GLL16(gp, lp) __builtin_amdgcn_global_load_lds( \
    (const __attribute__((address_space(1))) void*)(gp), \
    (__attribute__((address_space(3))) void*)(lp), 16, 0, 0)

// ---------------- elementwise f32 -> f16 convert (vectorized) ----------------
__global__ __launch_bounds__(256) void cvt_f16(const float* __restrict__ in,
                                               _Float16* __restrict__ out, int n8) {
    int idx = blockIdx.x * 256 + threadIdx.x;
    int stride = gridDim.x * 256;
    for (; idx < n8; idx += stride) {
        const float4* p = (const float4*)in + (size_t)idx * 2;
        float4 a = p[0], b = p[1];
        f16x8 o;
        o[0] = (_Float16)a.x; o[1] = (_Float16)a.y; o[2] = (_Float16)a.z; o[3] = (_Float16)a.w;
        o[4] = (_Float16)b.x; o[5] = (_Float16)b.y; o[6] = (_Float16)b.z; o[7] = (_Float16)b.w;
        *(f16x8*)(out + (size_t)idx * 8) = o;
    }
}

// ---------------- build block-diagonal omega, transposed, f16 ----------------
// obdT[c][k] = (c/64==k/64) ? omega[k%64][c%64] : 0     (1024x1024)
__global__ __launch_bounds__(256) void build_obdT(const float* __restrict__ omega,
                                                  _Float16* __restrict__ obdT) {
    int idx = blockIdx.x * 256 + threadIdx.x;   // over 1M
    int c = idx >> 10, k = idx & 1023;
    float v = ((c >> 6) == (k >> 6)) ? omega[(k & 63) * 64 + (c & 63)] : 0.f;
    obdT[idx] = (_Float16)v;
}

// ---------------- transpose 1024x1024 f32 -> f16 ----------------
__global__ __launch_bounds__(256) void transpose_cvt(const float* __restrict__ in,
                                                     _Float16* __restrict__ out) {
    __shared__ float tile[64][65];
    const int t = threadIdx.x;
    const int k0 = blockIdx.x * 64, n0 = blockIdx.y * 64;
#pragma unroll
    for (int j = 0; j < 16; j++) {
        int idx = j * 256 + t; int r = idx >> 6, c = idx & 63;
        tile[r][c] = in[(size_t)(k0 + r) * 1024 + n0 + c];
    }
    __syncthreads();
#pragma unroll
    for (int j = 0; j < 16; j++) {
        int idx = j * 256 + t; int rn = idx >> 6, ck = idx & 63;
        out[(size_t)(n0 + rn) * 1024 + k0 + ck] = (_Float16)tile[ck][rn];
    }
}

// ---------------- fold bias through omega ----------------
__global__ __launch_bounds__(256) void fold_bias(const float* __restrict__ b,
                                                 const float* __restrict__ omega,
                                                 float* __restrict__ bout) {
    int c = blockIdx.x * 256 + threadIdx.x;  // 0..1023
    int h = c >> 6, e = c & 63;
    float s = 0.f;
    for (int d = 0; d < 64; d++) s += b[h * 64 + d] * omega[d * 64 + e];
    bout[c] = s;
}

// ---------------- main GEMM: C[M][N] = A[M][K] @ Bt[N][K]^T (+bias, epilogue) ----------------
// EPI: 0 = linear -> f16 out, 1 = relu+eps -> f16 out, 2 = linear -> f32 out
// WRITE_T: write transposed per 64-wide head group: out[(nb*16+col/64)*64 + col%64][ldT] at l=row%4096
template<int EPI, bool WRITE_T>
__global__ __launch_bounds__(256) void gemm_bt(const _Float16* __restrict__ A,
                                               const _Float16* __restrict__ Bt,
                                               const float* __restrict__ bias,
                                               void* __restrict__ Cout,
                                               int M, int N, int K, int ldT) {
    __shared__ __align__(16) _Float16 Asm[128 * 32];
    __shared__ __align__(16) _Float16 Bsm[128 * 32];
    const int t = threadIdx.x, lane = t & 63, w = t >> 6;
    const int bm = blockIdx.y * 128, bn = blockIdx.x * 128;
    const int wm = (w >> 1) * 64, wn = (w & 1) * 64;
    const int r15 = lane & 15, slog = lane >> 4;

    int aoff[4], boff[4];
#pragma unroll
    for (int m = 0; m < 4; m++) {
        int ra = wm + m * 16 + r15;
        aoff[m] = ra * 32 + (slog ^ ((ra >> 1) & 3)) * 8;
        int rb = wn + m * 16 + r15;
        boff[m] = rb * 32 + (slog ^ ((rb >> 1) & 3)) * 8;
    }
    f32x4 zz = {0.f, 0.f, 0.f, 0.f};
    f32x4 acc[4][4];
#pragma unroll
    for (int m = 0; m < 4; m++)
#pragma unroll
        for (int n = 0; n < 4; n++) acc[m][n] = zz;

    for (int kt = 0; kt < K; kt += 32) {
        __syncthreads();
#pragma unroll
        for (int i = 0; i < 2; i++) {
            int seg = i * 256 + w * 64 + lane;
            int r = seg >> 2, sp = seg & 3;
            int sg = sp ^ ((r >> 1) & 3);   // pre-swizzled global source slot
            GLL16(A  + (size_t)(bm + r) * K + kt + sg * 8, Asm + (size_t)(i * 256 + w * 64) * 8);
            GLL16(Bt + (size_t)(bn + r) * K + kt + sg * 8, Bsm + (size_t)(i * 256 + w * 64) * 8);
        }
        __syncthreads();
        f16x8 av[4], bv[4];
#pragma unroll
        for (int m = 0; m < 4; m++) av[m] = *(const f16x8*)(Asm + aoff[m]);
#pragma unroll
        for (int n = 0; n < 4; n++) bv[n] = *(const f16x8*)(Bsm + boff[n]);
#pragma unroll
        for (int m = 0; m < 4; m++)
#pragma unroll
            for (int n = 0; n < 4; n++)
                acc[m][n] = __builtin_amdgcn_mfma_f32_16x16x32_f16(av[m], bv[n], acc[m][n], 0, 0, 0);
    }

#pragma unroll
    for (int m = 0; m < 4; m++) {
        int row0 = bm + wm + m * 16 + slog * 4;
#pragma unroll
        for (int n = 0; n < 4; n++) {
            int colg = bn + wn + n * 16 + r15;
            float bs = bias ? bias[colg] : 0.f;
            float v[4];
#pragma unroll
            for (int j = 0; j < 4; j++) {
                float x = acc[m][n][j] + bs;
                if (EPI == 1) x = fmaxf(x, 0.f) + EPSF;
                v[j] = x;
            }
            if (EPI == 2) {
                float* C = (float*)Cout;
#pragma unroll
                for (int j = 0; j < 4; j++) C[(size_t)(row0 + j) * N + colg] = v[j];
            } else if (!WRITE_T) {
                _Float16* C = (_Float16*)Cout;
#pragma unroll
                for (int j = 0; j < 4; j++) C[(size_t)(row0 + j) * N + colg] = (_Float16)v[j];
            } else {
                _Float16* C = (_Float16*)Cout;
                int hd = colg >> 6, d = colg & 63;
                int nb = row0 >> 12, l = row0 & 4095;
                f16x4 p;
#pragma unroll
                for (int j = 0; j < 4; j++) p[j] = (_Float16)v[j];
                *(f16x4*)(C + ((size_t)(nb * 16 + hd) * 64 + d) * (size_t)ldT + l) = p;
            }
        }
    }
}

// ---------------- ksum[head][d] = sum_l KphiT[head][d][l] ----------------
__global__ __launch_bounds__(256) void ksum_kernel(const _Float16* __restrict__ KphiT,
                                                   float* __restrict__ ksum) {
    const int t = threadIdx.x, lane = t & 63, w = t >> 6;
    const int gid = blockIdx.x;          // 0..1023
    const int head = gid >> 4;
    const int d = (gid & 15) * 4 + w;
    const _Float16* src = KphiT + ((size_t)head * 64 + d) * 4096;
    float s = 0.f;
#pragma unroll
    for (int i = 0; i < 8; i++) {
        f16x8 v = *(const f16x8*)(src + (size_t)(i * 64 + lane) * 8);
#pragma unroll
        for (int j = 0; j < 8; j++) s += (float)v[j];
    }
#pragma unroll
    for (int o = 32; o; o >>= 1) s += __shfl_xor(s, o, 64);
    if (lane == 0) ksum[(size_t)head * 64 + d] = s;
}

// ---------------- kv partials: kvpart[head][chunk][e][d] = sum_{l in chunk} V[l][e]*Kphi[l][d] ----------------
__global__ __launch_bounds__(256) void kvt_kernel(const _Float16* __restrict__ Vt,
                                                  const _Float16* __restrict__ KphiT,
                                                  float* __restrict__ kvpart) {
    const int t = threadIdx.x, lane = t & 63, w = t >> 6;
    const int head = blockIdx.y;
    const int l0 = blockIdx.x * 1024;
    __shared__ __align__(16) _Float16 As[64 * 128];
    __shared__ __align__(16) _Float16 Bs[64 * 128];
    const int r15 = lane & 15, slog = lane >> 4;
    f32x4 zz = {0.f, 0.f, 0.f, 0.f};
    f32x4 acc[4][4];
#pragma unroll
    for (int m = 0; m < 4; m++)
#pragma unroll
        for (int n = 0; n < 4; n++) acc[m][n] = zz;

    for (int it = 0; it < 8; it++) {
        __syncthreads();
        int lbase = l0 + it * 128;
#pragma unroll
        for (int i = 0; i < 4; i++) {
            int seg = i * 256 + w * 64 + lane;   // 1024 segs of 16B
            int r = seg >> 4, sp = seg & 15;
            int sg = sp ^ (r & 15);
            GLL16(Vt    + ((size_t)head * 64 + r) * 4096 + lbase + sg * 8, As + (size_t)(i * 256 + w * 64) * 8);
            GLL16(KphiT + ((size_t)head * 64 + r) * 4096 + lbase + sg * 8, Bs + (size_t)(i * 256 + w * 64) * 8);
        }
        __syncthreads();
        f16x8 av[4], bv[4];
#pragma unroll
        for (int m = 0; m < 4; m++) {
            int r = m * 16 + r15;
            int s = w * 4 + slog;                 // this wave's 32-wide k(l) slice
            int ph = s ^ (r & 15);
            av[m] = *(const f16x8*)(As + r * 128 + ph * 8);
            bv[m] = *(const f16x8*)(Bs + r * 128 + ph * 8);
        }
#pragma unroll
        for (int m = 0; m < 4; m++)
#pragma unroll
            for (int n = 0; n < 4; n++)
                acc[m][n] = __builtin_amdgcn_mfma_f32_16x16x32_f16(av[m], bv[n], acc[m][n], 0, 0, 0);
    }
    // block-reduce 4 waves into LDS (reuse As: 16 KiB = 64*64 f32)
    float* red = (float*)As;
    for (int ww = 0; ww < 4; ww++) {
        __syncthreads();
        if (w == ww) {
#pragma unroll
            for (int m = 0; m < 4; m++)
#pragma unroll
                for (int n = 0; n < 4; n++)
#pragma unroll
                    for (int j = 0; j < 4; j++) {
                        int row = m * 16 + slog * 4 + j, col = n * 16 + r15;
                        if (ww == 0) red[row * 64 + col] = acc[m][n][j];
                        else         red[row * 64 + col] += acc[m][n][j];
                    }
        }
    }
    __syncthreads();
    float* outp = kvpart + ((size_t)head * 4 + blockIdx.x) * 4096;
#pragma unroll
    for (int i = 0; i < 16; i++) { int idx = i * 256 + t; outp[idx] = red[idx]; }
}

// ---------------- reduce 4 chunks -> kvT[head][e][d] ----------------
__global__ __launch_bounds__(256) void kvreduce(const float* __restrict__ kvpart,
                                                float* __restrict__ kvT) {
    int head = blockIdx.x, t = threadIdx.x;
#pragma unroll
    for (int i = 0; i < 16; i++) {
        int idx = i * 256 + t;
        float s = 0.f;
#pragma unroll
        for (int c = 0; c < 4; c++) s += kvpart[((size_t)head * 4 + c) * 4096 + idx];
        kvT[(size_t)head * 4096 + idx] = s;
    }
}

// ---------------- numerator GEMM + denominator + divide -> U (f16) ----------------
__global__ __launch_bounds__(256) void numdiv_kernel(const _Float16* __restrict__ Qphi,
                                                     const float* __restrict__ kvT,
                                                     const float* __restrict__ ksum,
                                                     _Float16* __restrict__ U) {
    const int t = threadIdx.x, lane = t & 63, w = t >> 6;
    const int h = blockIdx.y;            // 0..15
    const int m0 = blockIdx.x * 256;     // global row
    const int nb = m0 >> 12;
    const int head = nb * 16 + h;
    __shared__ __align__(16) _Float16 Qs[256 * 64];
    __shared__ __align__(16) _Float16 Bs[64 * 64];
    __shared__ float ksl[64];

#pragma unroll
    for (int i = 0; i < 8; i++) {
        int seg = i * 256 + w * 64 + lane;   // 2048 segs of 16B
        int r = seg >> 3, sp = seg & 7;
        int sg = sp ^ (r & 7);
        GLL16(Qphi + (size_t)(m0 + r) * 1024 + h * 64 + sg * 8, Qs + (size_t)(i * 256 + w * 64) * 8);
    }
#pragma unroll
    for (int i = 0; i < 2; i++) {
        int sidx = i * 256 + t;              // phys 16B slot
        int r = sidx >> 3, p = sidx & 7;
        int sg = p ^ (r & 7);
        const float4* src = (const float4*)(kvT + (size_t)head * 4096 + r * 64 + sg * 8);
        float4 v0 = src[0], v1 = src[1];
        f16x8 o;
        o[0] = (_Float16)v0.x; o[1] = (_Float16)v0.y; o[2] = (_Float16)v0.z; o[3] = (_Float16)v0.w;
        o[4] = (_Float16)v1.x; o[5] = (_Float16)v1.y; o[6] = (_Float16)v1.z; o[7] = (_Float16)v1.w;
        *(f16x8*)(Bs + sidx * 8) = o;
    }
    if (t < 64) ksl[t] = ksum[(size_t)head * 64 + t];
    __syncthreads();

    const int r15 = lane & 15, slog = lane >> 4;
    f32x4 zz = {0.f, 0.f, 0.f, 0.f};
    f32x4 acc[4][4];
#pragma unroll
    for (int m = 0; m < 4; m++)
#pragma unroll
        for (int n = 0; n < 4; n++) acc[m][n] = zz;
    float dp[4] = {0.f, 0.f, 0.f, 0.f};

#pragma unroll
    for (int kk = 0; kk < 2; kk++) {
        float ks[8];
#pragma unroll
        for (int j = 0; j < 8; j++) ks[j] = ksl[kk * 32 + slog * 8 + j];
        f16x8 av[4], bv[4];
#pragma unroll
        for (int m = 0; m < 4; m++) {
            int r = w * 64 + m * 16 + r15;
            int ph = (kk * 4 + slog) ^ (r & 7);
            av[m] = *(const f16x8*)(Qs + r * 64 + ph * 8);
        }
#pragma unroll
        for (int n = 0; n < 4; n++) {
            int r = n * 16 + r15;
            int ph = (kk * 4 + slog) ^ (r & 7);
            bv[n] = *(const f16x8*)(Bs + r * 64 + ph * 8);
        }
#pragma unroll
        for (int m = 0; m < 4; m++)
#pragma unroll
            for (int j = 0; j < 8; j++) dp[m] += (float)av[m][j] * ks[j];
#pragma unroll
        for (int m = 0; m < 4; m++)
#pragma unroll
            for (int n = 0; n < 4; n++)
                acc[m][n] = __builtin_amdgcn_mfma_f32_16x16x32_f16(av[m], bv[n], acc[m][n], 0, 0, 0);
    }
#pragma unroll
    for (int m = 0; m < 4; m++) {
        dp[m] += __shfl_xor(dp[m], 16, 64);
        dp[m] += __shfl_xor(dp[m], 32, 64);
    }
#pragma unroll
    for (int m = 0; m < 4; m++) {
#pragma unroll
        for (int j = 0; j < 4; j++) {
            float den = __shfl(dp[m], slog * 4 + j, 64);
            float inv = __builtin_amdgcn_rcpf(den);
            int row = m0 + w * 64 + m * 16 + slog * 4 + j;
#pragma unroll
            for (int n = 0; n < 4; n++)
                U[(size_t)row * 1024 + h * 64 + n * 16 + r15] = (_Float16)(acc[m][n][j] * inv);
        }
    }
}

// ------------------------------------------------------------------------------------
extern "C" void kernel_launch(void* const* d_in, const int* in_sizes, int n_in,
                              void* d_out, int out_size, void* d_ws, size_t ws_size,
                              hipStream_t stream) {
    (void)in_sizes; (void)n_in; (void)out_size; (void)ws_size;
    const float* x     = (const float*)d_in[0];
    const float* y     = (const float*)d_in[1];
    const float* WQ    = (const float*)d_in[2];
    const float* bQ    = (const float*)d_in[3];
    const float* WK    = (const float*)d_in[4];
    const float* bK    = (const float*)d_in[5];
    const float* WV    = (const float*)d_in[6];
    const float* bV    = (const float*)d_in[7];
    const float* WO    = (const float*)d_in[8];
    const float* bO    = (const float*)d_in[9];
    const float* omega = (const float*)d_in[10];

    char* ws = (char*)d_ws;
    size_t off = 0;
    auto alloc = [&](size_t bytes) { void* p = ws + off; off += (bytes + 255) & ~(size_t)255; return p; };
    const size_t BIG = (size_t)16384 * 1024 * 2;    // 32 MiB f16
    _Float16* xb    = (_Float16*)alloc(BIG);        // also reused for U later
    _Float16* yb    = (_Float16*)alloc(BIG);
    _Float16* WQb   = (_Float16*)alloc(1024 * 1024 * 2);
    _Float16* WKb   = (_Float16*)alloc(1024 * 1024 * 2);
    _Float16* obdT  = (_Float16*)alloc(1024 * 1024 * 2);
    _Float16* Wqt   = (_Float16*)alloc(1024 * 1024 * 2);
    _Float16* Wkt   = (_Float16*)alloc(1024 * 1024 * 2);
    _Float16* Wvt   = (_Float16*)alloc(1024 * 1024 * 2);
    _Float16* Wot   = (_Float16*)alloc(1024 * 1024 * 2);
    float*    bQf   = (float*)alloc(1024 * 4);
    float*    bKf   = (float*)alloc(1024 * 4);
    _Float16* Qphi  = (_Float16*)alloc(BIG);
    _Float16* KphiT = (_Float16*)alloc(BIG);
    _Float16* Vt    = (_Float16*)alloc(BIG);
    float*    kvpart= (float*)alloc((size_t)256 * 4096 * 4);
    float*    kvT   = (float*)alloc((size_t)64 * 4096 * 4);
    float*    ksum  = (float*)alloc((size_t)64 * 64 * 4);
    _Float16* U     = xb;  // alias: xb dead after Qphi GEMM

    // 1. precision converts
    cvt_f16<<<2048, 256, 0, stream>>>(x, xb, 16384 * 1024 / 8);
    cvt_f16<<<2048, 256, 0, stream>>>(y, yb, 16384 * 1024 / 8);
    cvt_f16<<<512, 256, 0, stream>>>(WQ, WQb, 1024 * 1024 / 8);
    cvt_f16<<<512, 256, 0, stream>>>(WK, WKb, 1024 * 1024 / 8);
    // 2. omega block-diag (transposed) + weight transposes + bias folds
    build_obdT<<<4096, 256, 0, stream>>>(omega, obdT);
    transpose_cvt<<<dim3(16, 16), 256, 0, stream>>>(WV, Wvt);
    transpose_cvt<<<dim3(16, 16), 256, 0, stream>>>(WO, Wot);
    fold_bias<<<4, 256, 0, stream>>>(bQ, omega, bQf);
    fold_bias<<<4, 256, 0, stream>>>(bK, omega, bKf);
    // 3. fold omega into WQ/WK (outputs already transposed for the Bt operand)
    gemm_bt<0, true><<<dim3(8, 8), 256, 0, stream>>>(WQb, obdT, nullptr, Wqt, 1024, 1024, 1024, 1024);
    gemm_bt<0, true><<<dim3(8, 8), 256, 0, stream>>>(WKb, obdT, nullptr, Wkt, 1024, 1024, 1024, 1024);
    // 4. projections (+phi for Q/K); K and V written transposed per head
    gemm_bt<1, false><<<dim3(8, 128), 256, 0, stream>>>(xb, Wqt, bQf, Qphi, 16384, 1024, 1024, 0);
    gemm_bt<1, true ><<<dim3(8, 128), 256, 0, stream>>>(yb, Wkt, bKf, KphiT, 16384, 1024, 1024, 4096);
    gemm_bt<0, true ><<<dim3(8, 128), 256, 0, stream>>>(yb, Wvt, bV, Vt, 16384, 1024, 1024, 4096);
    // 5. per-head reductions
    ksum_kernel<<<1024, 256, 0, stream>>>(KphiT, ksum);
    kvt_kernel<<<dim3(4, 64), 256, 0, stream>>>(Vt, KphiT, kvpart);
    kvreduce<<<64, 256, 0, stream>>>(kvpart, kvT);
    // 6. numerator / denominator / divide
    numdiv_kernel<<<dim3(64, 16), 256, 0, stream>>>(Qphi, kvT, ksum, U);
    // 7. output projection
    gemm_bt<2, false><<<dim3(8, 128), 256, 0, stream>>>(U, Wot, bO, d_out, 16384, 1024, 1024, 0);
}

// Round 2
// 333.155 us; speedup vs baseline: 1.2677x; 1.2677x over previous
//
#include <hip/hip_runtime.h>

#define EPSF 1e-6f

typedef _Float16 f16x8 __attribute__((ext_vector_type(8)));
typedef _Float16 f16x4 __attribute__((ext_vector_type(4)));
typedef float    f32x4 __attribute__((ext_vector_type(4)));

#define GLL16(gp, lp) __builtin_amdgcn_global_load_lds( \
    (const __attribute__((address_space(1))) void*)(gp), \
    (__attribute__((address_space(3))) void*)(lp), 16, 0, 0)

// ---------------- elementwise f32 -> f16 convert (vectorized) ----------------
__global__ __launch_bounds__(256) void cvt_f16(const float* __restrict__ in,
                                               _Float16* __restrict__ out, int n8) {
    int idx = blockIdx.x * 256 + threadIdx.x;
    int stride = gridDim.x * 256;
    for (; idx < n8; idx += stride) {
        const float4* p = (const float4*)in + (size_t)idx * 2;
        float4 a = p[0], b = p[1];
        f16x8 o;
        o[0] = (_Float16)a.x; o[1] = (_Float16)a.y; o[2] = (_Float16)a.z; o[3] = (_Float16)a.w;
        o[4] = (_Float16)b.x; o[5] = (_Float16)b.y; o[6] = (_Float16)b.z; o[7] = (_Float16)b.w;
        *(f16x8*)(out + (size_t)idx * 8) = o;
    }
}

// ---------------- build block-diagonal omega, transposed, f16 ----------------
__global__ __launch_bounds__(256) void build_obdT(const float* __restrict__ omega,
                                                  _Float16* __restrict__ obdT) {
    int idx = blockIdx.x * 256 + threadIdx.x;   // over 1M
    int c = idx >> 10, k = idx & 1023;
    float v = ((c >> 6) == (k >> 6)) ? omega[(k & 63) * 64 + (c & 63)] : 0.f;
    obdT[idx] = (_Float16)v;
}

// ---------------- transpose 1024x1024 f32 -> f16 ----------------
__global__ __launch_bounds__(256) void transpose_cvt(const float* __restrict__ in,
                                                     _Float16* __restrict__ out) {
    __shared__ float tile[64][65];
    const int t = threadIdx.x;
    const int k0 = blockIdx.x * 64, n0 = blockIdx.y * 64;
#pragma unroll
    for (int j = 0; j < 16; j++) {
        int idx = j * 256 + t; int r = idx >> 6, c = idx & 63;
        tile[r][c] = in[(size_t)(k0 + r) * 1024 + n0 + c];
    }
    __syncthreads();
#pragma unroll
    for (int j = 0; j < 16; j++) {
        int idx = j * 256 + t; int rn = idx >> 6, ck = idx & 63;
        out[(size_t)(n0 + rn) * 1024 + k0 + ck] = (_Float16)tile[ck][rn];
    }
}

// ---------------- fold bias through omega ----------------
__global__ __launch_bounds__(256) void fold_bias(const float* __restrict__ b,
                                                 const float* __restrict__ omega,
                                                 float* __restrict__ bout) {
    int c = blockIdx.x * 256 + threadIdx.x;  // 0..1023
    int h = c >> 6, e = c & 63;
    float s = 0.f;
    for (int d = 0; d < 64; d++) s += b[h * 64 + d] * omega[d * 64 + e];
    bout[c] = s;
}

__global__ __launch_bounds__(256) void copy_f32(const float* __restrict__ in,
                                                float* __restrict__ out, int n) {
    int i = blockIdx.x * 256 + threadIdx.x;
    if (i < n) out[i] = in[i];
}

// ---------------- small GEMM (128^2 m97-style) used for weight folds ----------------
// EPI 0 + WRITE_T(ldT): writes C^T rows = out features -> Bt layout for the big GEMM
template<int EPI, bool WRITE_T>
__global__ __launch_bounds__(256) void gemm_bt(const _Float16* __restrict__ A,
                                               const _Float16* __restrict__ Bt,
                                               const float* __restrict__ bias,
                                               void* __restrict__ Cout,
                                               int M, int N, int K, int ldT) {
    __shared__ __align__(16) _Float16 Asm[128 * 32];
    __shared__ __align__(16) _Float16 Bsm[128 * 32];
    const int t = threadIdx.x, lane = t & 63, w = t >> 6;
    const int bm = blockIdx.y * 128, bn = blockIdx.x * 128;
    const int wm = (w >> 1) * 64, wn = (w & 1) * 64;
    const int r15 = lane & 15, slog = lane >> 4;

    int aoff[4], boff[4];
#pragma unroll
    for (int m = 0; m < 4; m++) {
        int ra = wm + m * 16 + r15;
        aoff[m] = ra * 32 + (slog ^ ((ra >> 1) & 3)) * 8;
        int rb = wn + m * 16 + r15;
        boff[m] = rb * 32 + (slog ^ ((rb >> 1) & 3)) * 8;
    }
    f32x4 zz = {0.f, 0.f, 0.f, 0.f};
    f32x4 acc[4][4];
#pragma unroll
    for (int m = 0; m < 4; m++)
#pragma unroll
        for (int n = 0; n < 4; n++) acc[m][n] = zz;

    for (int kt = 0; kt < K; kt += 32) {
        __syncthreads();
#pragma unroll
        for (int i = 0; i < 2; i++) {
            int seg = i * 256 + w * 64 + lane;
            int r = seg >> 2, sp = seg & 3;
            int sg = sp ^ ((r >> 1) & 3);
            GLL16(A  + (size_t)(bm + r) * K + kt + sg * 8, Asm + (size_t)(i * 256 + w * 64) * 8);
            GLL16(Bt + (size_t)(bn + r) * K + kt + sg * 8, Bsm + (size_t)(i * 256 + w * 64) * 8);
        }
        __syncthreads();
        f16x8 av[4], bv[4];
#pragma unroll
        for (int m = 0; m < 4; m++) av[m] = *(const f16x8*)(Asm + aoff[m]);
#pragma unroll
        for (int n = 0; n < 4; n++) bv[n] = *(const f16x8*)(Bsm + boff[n]);
#pragma unroll
        for (int m = 0; m < 4; m++)
#pragma unroll
            for (int n = 0; n < 4; n++)
                acc[m][n] = __builtin_amdgcn_mfma_f32_16x16x32_f16(av[m], bv[n], acc[m][n], 0, 0, 0);
    }

#pragma unroll
    for (int m = 0; m < 4; m++) {
        int row0 = bm + wm + m * 16 + slog * 4;
#pragma unroll
        for (int n = 0; n < 4; n++) {
            int colg = bn + wn + n * 16 + r15;
            float bs = bias ? bias[colg] : 0.f;
            float v[4];
#pragma unroll
            for (int j = 0; j < 4; j++) {
                float x = acc[m][n][j] + bs;
                if (EPI == 1) x = fmaxf(x, 0.f) + EPSF;
                v[j] = x;
            }
            if (!WRITE_T) {
                _Float16* C = (_Float16*)Cout;
#pragma unroll
                for (int j = 0; j < 4; j++) C[(size_t)(row0 + j) * N + colg] = (_Float16)v[j];
            } else {
                _Float16* C = (_Float16*)Cout;
                int hd = colg >> 6, d = colg & 63;
                int nb = row0 >> 12, l = row0 & 4095;
                f16x4 p;
#pragma unroll
                for (int j = 0; j < 4; j++) p[j] = (_Float16)v[j];
                *(f16x4*)(C + ((size_t)(nb * 16 + hd) * 64 + d) * (size_t)ldT + l) = p;
            }
        }
    }
}

// ---------------- big GEMM: 256x256 tile, BK=64, 8 waves, 128KiB LDS dbuf ----------------
// LDS layout per buffer: A[256][64] f16 at +0, B[256][64] f16 at +32768.
// Swizzle: phys byte within row = (col*2) ^ ((row&7)<<4); gll writes linearly with
// pre-swizzled global source (rule #21), ds_read applies the same XOR.
// EPI: 1 = relu+eps -> f16 [M][N];  2 = linear -> f32 [M][N];
//      3 = split (col<1024: relu+eps -> out0 transposed; else linear -> out1 transposed)
template<int EPI>
__global__ __launch_bounds__(512, 2) void gemm256(const _Float16* __restrict__ A,
                                                  const _Float16* __restrict__ Bt,
                                                  const float* __restrict__ bias,
                                                  void* __restrict__ out0,
                                                  void* __restrict__ out1,
                                                  int M, int N, int K, int nbn) {
    __shared__ __align__(16) char lds[131072];
    const int t = threadIdx.x, lane = t & 63, w = t >> 6;
    // bijective XCD swizzle (caller guarantees gridDim.x % 8 == 0)
    const int nwg = gridDim.x;
    const int f = (blockIdx.x & 7) * (nwg >> 3) + (blockIdx.x >> 3);
    const int bm = (f / nbn) * 256, bn = (f % nbn) * 256;
    const int wm = (w & 1) * 128, wn = (w >> 1) * 64;
    const int r15 = lane & 15, hi = lane >> 4;
    const int rr = lane >> 3;                 // staging: row within 8-row chunk
    const int cc = ((lane & 7) ^ rr) * 8;     // staging: pre-swizzled global col (f16)
    const int sw = (r15 & 7) << 4;            // ds_read swizzle XOR (bytes)

    f32x4 acc[8][4];
#pragma unroll
    for (int m = 0; m < 8; m++)
#pragma unroll
        for (int n = 0; n < 4; n++) acc[m][n] = (f32x4){0.f, 0.f, 0.f, 0.f};

    auto stage = [&](int kt, int buf) {
#pragma unroll
        for (int j = 0; j < 4; j++) {
            int ch = j * 8 + w;               // 32 chunks of 8 rows
            int row = ch * 8 + rr;
            GLL16(A  + (size_t)(bm + row) * K + kt + cc, lds + buf * 65536 + ch * 1024);
            GLL16(Bt + (size_t)(bn + row) * K + kt + cc, lds + buf * 65536 + 32768 + ch * 1024);
        }
    };

    const int NT = K >> 6;
    stage(0, 0);
    for (int T = 0; T < NT; ++T) {
        const int cur = T & 1;
        __syncthreads();                       // drains vmcnt: tile T landed, T-1 reads done
        if (T + 1 < NT) stage((T + 1) << 6, cur ^ 1);
        const char* La = lds + cur * 65536;
        const char* Lb = La + 32768;
        f16x8 bv[4][2];
#pragma unroll
        for (int n = 0; n < 4; n++)
#pragma unroll
            for (int ks = 0; ks < 2; ks++) {
                int r = wn + n * 16 + r15;
                bv[n][ks] = *(const f16x8*)(Lb + r * 128 + ((ks * 64 + hi * 16) ^ sw));
            }
#pragma unroll
        for (int g = 0; g < 4; g++) {
            f16x8 av[2][2];
#pragma unroll
            for (int mm = 0; mm < 2; mm++)
#pragma unroll
                for (int ks = 0; ks < 2; ks++) {
                    int r = wm + (g * 2 + mm) * 16 + r15;
                    av[mm][ks] = *(const f16x8*)(La + r * 128 + ((ks * 64 + hi * 16) ^ sw));
                }
            __builtin_amdgcn_s_setprio(1);
#pragma unroll
            for (int mm = 0; mm < 2; mm++)
#pragma unroll
                for (int n = 0; n < 4; n++)
#pragma unroll
                    for (int ks = 0; ks < 2; ks++)
                        acc[g * 2 + mm][n] = __builtin_amdgcn_mfma_f32_16x16x32_f16(
                            av[mm][ks], bv[n][ks], acc[g * 2 + mm][n], 0, 0, 0);
            __builtin_amdgcn_s_setprio(0);
        }
    }

#pragma unroll
    for (int m = 0; m < 8; m++) {
        int row0 = bm + wm + m * 16 + hi * 4;
#pragma unroll
        for (int n = 0; n < 4; n++) {
            int colg = bn + wn + n * 16 + r15;
            float bs = bias ? bias[colg] : 0.f;
            float v[4];
#pragma unroll
            for (int j = 0; j < 4; j++) {
                float xv = acc[m][n][j] + bs;
                if (EPI == 1 || (EPI == 3 && colg < 1024)) xv = fmaxf(xv, 0.f) + EPSF;
                v[j] = xv;
            }
            if (EPI == 2) {
                float* C = (float*)out0;
#pragma unroll
                for (int j = 0; j < 4; j++) C[(size_t)(row0 + j) * N + colg] = v[j];
            } else if (EPI == 1) {
                _Float16* C = (_Float16*)out0;
#pragma unroll
                for (int j = 0; j < 4; j++) C[(size_t)(row0 + j) * N + colg] = (_Float16)v[j];
            } else {
                _Float16* C; int hd;
                if (colg < 1024) { C = (_Float16*)out0; hd = colg >> 6; }
                else             { C = (_Float16*)out1; hd = (colg - 1024) >> 6; }
                int d = colg & 63, nb = row0 >> 12, l = row0 & 4095;
                f16x4 p;
#pragma unroll
                for (int j = 0; j < 4; j++) p[j] = (_Float16)v[j];
                *(f16x4*)(C + ((size_t)(nb * 16 + hd) * 64 + d) * 4096 + l) = p;
            }
        }
    }
}

// ---------------- ksum[head][d] = sum_l KphiT[head][d][l] ----------------
__global__ __launch_bounds__(256) void ksum_kernel(const _Float16* __restrict__ KphiT,
                                                   float* __restrict__ ksum) {
    const int t = threadIdx.x, lane = t & 63, w = t >> 6;
    const int gid = blockIdx.x;          // 0..1023
    const int head = gid >> 4;
    const int d = (gid & 15) * 4 + w;
    const _Float16* src = KphiT + ((size_t)head * 64 + d) * 4096;
    float s = 0.f;
#pragma unroll
    for (int i = 0; i < 8; i++) {
        f16x8 v = *(const f16x8*)(src + (size_t)(i * 64 + lane) * 8);
#pragma unroll
        for (int j = 0; j < 8; j++) s += (float)v[j];
    }
#pragma unroll
    for (int o = 32; o; o >>= 1) s += __shfl_xor(s, o, 64);
    if (lane == 0) ksum[(size_t)head * 64 + d] = s;
}

// ---------------- kv partials ----------------
__global__ __launch_bounds__(256) void kvt_kernel(const _Float16* __restrict__ Vt,
                                                  const _Float16* __restrict__ KphiT,
                                                  float* __restrict__ kvpart) {
    const int t = threadIdx.x, lane = t & 63, w = t >> 6;
    const int head = blockIdx.y;
    const int l0 = blockIdx.x * 1024;
    __shared__ __align__(16) _Float16 As[64 * 128];
    __shared__ __align__(16) _Float16 Bs[64 * 128];
    const int r15 = lane & 15, slog = lane >> 4;
    f32x4 zz = {0.f, 0.f, 0.f, 0.f};
    f32x4 acc[4][4];
#pragma unroll
    for (int m = 0; m < 4; m++)
#pragma unroll
        for (int n = 0; n < 4; n++) acc[m][n] = zz;

    for (int it = 0; it < 8; it++) {
        __syncthreads();
        int lbase = l0 + it * 128;
#pragma unroll
        for (int i = 0; i < 4; i++) {
            int seg = i * 256 + w * 64 + lane;
            int r = seg >> 4, sp = seg & 15;
            int sg = sp ^ (r & 15);
            GLL16(Vt    + ((size_t)head * 64 + r) * 4096 + lbase + sg * 8, As + (size_t)(i * 256 + w * 64) * 8);
            GLL16(KphiT + ((size_t)head * 64 + r) * 4096 + lbase + sg * 8, Bs + (size_t)(i * 256 + w * 64) * 8);
        }
        __syncthreads();
        f16x8 av[4], bv[4];
#pragma unroll
        for (int m = 0; m < 4; m++) {
            int r = m * 16 + r15;
            int s = w * 4 + slog;
            int ph = s ^ (r & 15);
            av[m] = *(const f16x8*)(As + r * 128 + ph * 8);
            bv[m] = *(const f16x8*)(Bs + r * 128 + ph * 8);
        }
#pragma unroll
        for (int m = 0; m < 4; m++)
#pragma unroll
            for (int n = 0; n < 4; n++)
                acc[m][n] = __builtin_amdgcn_mfma_f32_16x16x32_f16(av[m], bv[n], acc[m][n], 0, 0, 0);
    }
    float* red = (float*)As;
    for (int ww = 0; ww < 4; ww++) {
        __syncthreads();
        if (w == ww) {
#pragma unroll
            for (int m = 0; m < 4; m++)
#pragma unroll
                for (int n = 0; n < 4; n++)
#pragma unroll
                    for (int j = 0; j < 4; j++) {
                        int row = m * 16 + slog * 4 + j, col = n * 16 + r15;
                        if (ww == 0) red[row * 64 + col] = acc[m][n][j];
                        else         red[row * 64 + col] += acc[m][n][j];
                    }
        }
    }
    __syncthreads();
    float* outp = kvpart + ((size_t)head * 4 + blockIdx.x) * 4096;
#pragma unroll
    for (int i = 0; i < 16; i++) { int idx = i * 256 + t; outp[idx] = red[idx]; }
}

__global__ __launch_bounds__(256) void kvreduce(const float* __restrict__ kvpart,
                                                float* __restrict__ kvT) {
    int head = blockIdx.x, t = threadIdx.x;
#pragma unroll
    for (int i = 0; i < 16; i++) {
        int idx = i * 256 + t;
        float s = 0.f;
#pragma unroll
        for (int c = 0; c < 4; c++) s += kvpart[((size_t)head * 4 + c) * 4096 + idx];
        kvT[(size_t)head * 4096 + idx] = s;
    }
}

// ---------------- numerator GEMM + denominator + divide -> U (f16) ----------------
__global__ __launch_bounds__(256) void numdiv_kernel(const _Float16* __restrict__ Qphi,
                                                     const float* __restrict__ kvT,
                                                     const float* __restrict__ ksum,
                                                     _Float16* __restrict__ U) {
    const int t = threadIdx.x, lane = t & 63, w = t >> 6;
    const int h = blockIdx.y;
    const int m0 = blockIdx.x * 256;
    const int nb = m0 >> 12;
    const int head = nb * 16 + h;
    __shared__ __align__(16) _Float16 Qs[256 * 64];
    __shared__ __align__(16) _Float16 Bs[64 * 64];
    __shared__ float ksl[64];

#pragma unroll
    for (int i = 0; i < 8; i++) {
        int seg = i * 256 + w * 64 + lane;
        int r = seg >> 3, sp = seg & 7;
        int sg = sp ^ (r & 7);
        GLL16(Qphi + (size_t)(m0 + r) * 1024 + h * 64 + sg * 8, Qs + (size_t)(i * 256 + w * 64) * 8);
    }
#pragma unroll
    for (int i = 0; i < 2; i++) {
        int sidx = i * 256 + t;
        int r = sidx >> 3, p = sidx & 7;
        int sg = p ^ (r & 7);
        const float4* src = (const float4*)(kvT + (size_t)head * 4096 + r * 64 + sg * 8);
        float4 v0 = src[0], v1 = src[1];
        f16x8 o;
        o[0] = (_Float16)v0.x; o[1] = (_Float16)v0.y; o[2] = (_Float16)v0.z; o[3] = (_Float16)v0.w;
        o[4] = (_Float16)v1.x; o[5] = (_Float16)v1.y; o[6] = (_Float16)v1.z; o[7] = (_Float16)v1.w;
        *(f16x8*)(Bs + sidx * 8) = o;
    }
    if (t < 64) ksl[t] = ksum[(size_t)head * 64 + t];
    __syncthreads();

    const int r15 = lane & 15, slog = lane >> 4;
    f32x4 zz = {0.f, 0.f, 0.f, 0.f};
    f32x4 acc[4][4];
#pragma unroll
    for (int m = 0; m < 4; m++)
#pragma unroll
        for (int n = 0; n < 4; n++) acc[m][n] = zz;
    float dp[4] = {0.f, 0.f, 0.f, 0.f};

#pragma unroll
    for (int kk = 0; kk < 2; kk++) {
        float ks[8];
#pragma unroll
        for (int j = 0; j < 8; j++) ks[j] = ksl[kk * 32 + slog * 8 + j];
        f16x8 av[4], bv[4];
#pragma unroll
        for (int m = 0; m < 4; m++) {
            int r = w * 64 + m * 16 + r15;
            int ph = (kk * 4 + slog) ^ (r & 7);
            av[m] = *(const f16x8*)(Qs + r * 64 + ph * 8);
        }
#pragma unroll
        for (int n = 0; n < 4; n++) {
            int r = n * 16 + r15;
            int ph = (kk * 4 + slog) ^ (r & 7);
            bv[n] = *(const f16x8*)(Bs + r * 64 + ph * 8);
        }
#pragma unroll
        for (int m = 0; m < 4; m++)
#pragma unroll
            for (int j = 0; j < 8; j++) dp[m] += (float)av[m][j] * ks[j];
#pragma unroll
        for (int m = 0; m < 4; m++)
#pragma unroll
            for (int n = 0; n < 4; n++)
                acc[m][n] = __builtin_amdgcn_mfma_f32_16x16x32_f16(av[m], bv[n], acc[m][n], 0, 0, 0);
    }
#pragma unroll
    for (int m = 0; m < 4; m++) {
        dp[m] += __shfl_xor(dp[m], 16, 64);
        dp[m] += __shfl_xor(dp[m], 32, 64);
    }
#pragma unroll
    for (int m = 0; m < 4; m++) {
#pragma unroll
        for (int j = 0; j < 4; j++) {
            float den = __shfl(dp[m], slog * 4 + j, 64);
            float inv = __builtin_amdgcn_rcpf(den);
            int row = m0 + w * 64 + m * 16 + slog * 4 + j;
#pragma unroll
            for (int n = 0; n < 4; n++)
                U[(size_t)row * 1024 + h * 64 + n * 16 + r15] = (_Float16)(acc[m][n][j] * inv);
        }
    }
}

// ------------------------------------------------------------------------------------
extern "C" void kernel_launch(void* const* d_in, const int* in_sizes, int n_in,
                              void* d_out, int out_size, void* d_ws, size_t ws_size,
                              hipStream_t stream) {
    (void)in_sizes; (void)n_in; (void)out_size; (void)ws_size;
    const float* x     = (const float*)d_in[0];
    const float* y     = (const float*)d_in[1];
    const float* WQ    = (const float*)d_in[2];
    const float* bQ    = (const float*)d_in[3];
    const float* WK    = (const float*)d_in[4];
    const float* bK    = (const float*)d_in[5];
    const float* WV    = (const float*)d_in[6];
    const float* bV    = (const float*)d_in[7];
    const float* WO    = (const float*)d_in[8];
    const float* bO    = (const float*)d_in[9];
    const float* omega = (const float*)d_in[10];

    char* ws = (char*)d_ws;
    size_t off = 0;
    auto alloc = [&](size_t bytes) { void* p = ws + off; off += (bytes + 255) & ~(size_t)255; return p; };
    const size_t BIG = (size_t)16384 * 1024 * 2;    // 32 MiB f16
    _Float16* xb    = (_Float16*)alloc(BIG);        // reused for U later
    _Float16* yb    = (_Float16*)alloc(BIG);
    _Float16* WQb   = (_Float16*)alloc(1024 * 1024 * 2);
    _Float16* WKb   = (_Float16*)alloc(1024 * 1024 * 2);
    _Float16* obdT  = (_Float16*)alloc(1024 * 1024 * 2);
    _Float16* Wqt   = (_Float16*)alloc(1024 * 1024 * 2);
    _Float16* Wkvt  = (_Float16*)alloc((size_t)2048 * 1024 * 2);  // rows 0..1023: K-fold, 1024..2047: V^T
    _Float16* Wot   = (_Float16*)alloc(1024 * 1024 * 2);
    float*    bQf   = (float*)alloc(1024 * 4);
    float*    bkv   = (float*)alloc(2048 * 4);
    _Float16* Qphi  = (_Float16*)alloc(BIG);
    _Float16* KphiT = (_Float16*)alloc(BIG);
    _Float16* Vt    = (_Float16*)alloc(BIG);
    float*    kvpart= (float*)alloc((size_t)256 * 4096 * 4);
    float*    kvT   = (float*)alloc((size_t)64 * 4096 * 4);
    float*    ksum  = (float*)alloc((size_t)64 * 64 * 4);
    _Float16* U     = xb;  // alias: xb dead after Qphi GEMM

    // 1. precision converts
    cvt_f16<<<2048, 256, 0, stream>>>(x, xb, 16384 * 1024 / 8);
    cvt_f16<<<2048, 256, 0, stream>>>(y, yb, 16384 * 1024 / 8);
    cvt_f16<<<512, 256, 0, stream>>>(WQ, WQb, 1024 * 1024 / 8);
    cvt_f16<<<512, 256, 0, stream>>>(WK, WKb, 1024 * 1024 / 8);
    // 2. omega block-diag (transposed) + weight transposes + bias folds
    build_obdT<<<4096, 256, 0, stream>>>(omega, obdT);
    transpose_cvt<<<dim3(16, 16), 256, 0, stream>>>(WV, Wkvt + (size_t)1024 * 1024);
    transpose_cvt<<<dim3(16, 16), 256, 0, stream>>>(WO, Wot);
    fold_bias<<<4, 256, 0, stream>>>(bQ, omega, bQf);
    fold_bias<<<4, 256, 0, stream>>>(bK, omega, bkv);
    copy_f32<<<4, 256, 0, stream>>>(bV, bkv + 1024, 1024);
    // 3. fold omega into WQ/WK (outputs transposed into Bt layout)
    gemm_bt<0, true><<<dim3(8, 8), 256, 0, stream>>>(WQb, obdT, nullptr, Wqt, 1024, 1024, 1024, 1024);
    gemm_bt<0, true><<<dim3(8, 8), 256, 0, stream>>>(WKb, obdT, nullptr, Wkvt, 1024, 1024, 1024, 1024);
    // 4. projections: Q (relu+eps), K|V merged (K relu+eps transposed, V linear transposed)
    gemm256<1><<<256, 512, 0, stream>>>(xb, Wqt, bQf, Qphi, nullptr, 16384, 1024, 1024, 4);
    gemm256<3><<<512, 512, 0, stream>>>(yb, Wkvt, bkv, KphiT, Vt, 16384, 2048, 1024, 8);
    // 5. per-head reductions
    ksum_kernel<<<1024, 256, 0, stream>>>(KphiT, ksum);
    kvt_kernel<<<dim3(4, 64), 256, 0, stream>>>(Vt, KphiT, kvpart);
    kvreduce<<<64, 256, 0, stream>>>(kvpart, kvT);
    // 6. numerator / denominator / divide
    numdiv_kernel<<<dim3(64, 16), 256, 0, stream>>>(Qphi, kvT, ksum, U);
    // 7. output projection
    gemm256<2><<<256, 512, 0, stream>>>(U, Wot, bO, d_out, nullptr, 16384, 1024, 1024, 4);
}

// Round 3
// 287.247 us; speedup vs baseline: 1.4703x; 1.1598x over previous
//
#include <hip/hip_runtime.h>

#define EPSF 1e-6f

typedef _Float16 f16x8 __attribute__((ext_vector_type(8)));
typedef _Float16 f16x4 __attribute__((ext_vector_type(4)));
typedef float    f32x4 __attribute__((ext_vector_type(4)));

#define GLL16(gp, lp) __builtin_amdgcn_global_load_lds( \
    (const __attribute__((address_space(1))) void*)(gp), \
    (__attribute__((address_space(3))) void*)(lp), 16, 0, 0)

// ---------------- elementwise f32 -> f16 convert (vectorized) ----------------
__global__ __launch_bounds__(256) void cvt_f16(const float* __restrict__ in,
                                               _Float16* __restrict__ out, int n8) {
    int idx = blockIdx.x * 256 + threadIdx.x;
    int stride = gridDim.x * 256;
    for (; idx < n8; idx += stride) {
        const float4* p = (const float4*)in + (size_t)idx * 2;
        float4 a = p[0], b = p[1];
        f16x8 o;
        o[0] = (_Float16)a.x; o[1] = (_Float16)a.y; o[2] = (_Float16)a.z; o[3] = (_Float16)a.w;
        o[4] = (_Float16)b.x; o[5] = (_Float16)b.y; o[6] = (_Float16)b.z; o[7] = (_Float16)b.w;
        *(f16x8*)(out + (size_t)idx * 8) = o;
    }
}

// ---------------- build block-diagonal omega, transposed, f16 ----------------
__global__ __launch_bounds__(256) void build_obdT(const float* __restrict__ omega,
                                                  _Float16* __restrict__ obdT) {
    int idx = blockIdx.x * 256 + threadIdx.x;   // over 1M
    int c = idx >> 10, k = idx & 1023;
    float v = ((c >> 6) == (k >> 6)) ? omega[(k & 63) * 64 + (c & 63)] : 0.f;
    obdT[idx] = (_Float16)v;
}

// ---------------- transpose 1024x1024 f32 -> f16 ----------------
__global__ __launch_bounds__(256) void transpose_cvt(const float* __restrict__ in,
                                                     _Float16* __restrict__ out) {
    __shared__ float tile[64][65];
    const int t = threadIdx.x;
    const int k0 = blockIdx.x * 64, n0 = blockIdx.y * 64;
#pragma unroll
    for (int j = 0; j < 16; j++) {
        int idx = j * 256 + t; int r = idx >> 6, c = idx & 63;
        tile[r][c] = in[(size_t)(k0 + r) * 1024 + n0 + c];
    }
    __syncthreads();
#pragma unroll
    for (int j = 0; j < 16; j++) {
        int idx = j * 256 + t; int rn = idx >> 6, ck = idx & 63;
        out[(size_t)(n0 + rn) * 1024 + k0 + ck] = (_Float16)tile[ck][rn];
    }
}

// ---------------- fold bias through omega ----------------
__global__ __launch_bounds__(256) void fold_bias(const float* __restrict__ b,
                                                 const float* __restrict__ omega,
                                                 float* __restrict__ bout) {
    int c = blockIdx.x * 256 + threadIdx.x;  // 0..1023
    int h = c >> 6, e = c & 63;
    float s = 0.f;
    for (int d = 0; d < 64; d++) s += b[h * 64 + d] * omega[d * 64 + e];
    bout[c] = s;
}

__global__ __launch_bounds__(256) void copy_f32(const float* __restrict__ in,
                                                float* __restrict__ out, int n) {
    int i = blockIdx.x * 256 + threadIdx.x;
    if (i < n) out[i] = in[i];
}

// ---------------- fold GEMM (m97 128^2 structure): [WQ;WK](2048x1024) @ obdT^T ----------------
// writes transposed: out = Wq'(^T) rows=out-feature, cols=in-feature; row0<1024 -> out0 else out1
__global__ __launch_bounds__(256) void gemm_fold(const _Float16* __restrict__ A,
                                                 const _Float16* __restrict__ Bt,
                                                 _Float16* __restrict__ out0,
                                                 _Float16* __restrict__ out1) {
    const int K = 1024;
    __shared__ __align__(16) _Float16 Asm[128 * 32];
    __shared__ __align__(16) _Float16 Bsm[128 * 32];
    const int t = threadIdx.x, lane = t & 63, w = t >> 6;
    const int bm = blockIdx.y * 128, bn = blockIdx.x * 128;
    const int wm = (w >> 1) * 64, wn = (w & 1) * 64;
    const int r15 = lane & 15, slog = lane >> 4;

    int aoff[4], boff[4];
#pragma unroll
    for (int m = 0; m < 4; m++) {
        int ra = wm + m * 16 + r15;
        aoff[m] = ra * 32 + (slog ^ ((ra >> 1) & 3)) * 8;
        int rb = wn + m * 16 + r15;
        boff[m] = rb * 32 + (slog ^ ((rb >> 1) & 3)) * 8;
    }
    f32x4 acc[4][4];
#pragma unroll
    for (int m = 0; m < 4; m++)
#pragma unroll
        for (int n = 0; n < 4; n++) acc[m][n] = (f32x4){0.f, 0.f, 0.f, 0.f};

    for (int kt = 0; kt < K; kt += 32) {
        __syncthreads();
#pragma unroll
        for (int i = 0; i < 2; i++) {
            int seg = i * 256 + w * 64 + lane;
            int r = seg >> 2, sp = seg & 3;
            int sg = sp ^ ((r >> 1) & 3);
            GLL16(A  + (size_t)(bm + r) * K + kt + sg * 8, Asm + (size_t)(i * 256 + w * 64) * 8);
            GLL16(Bt + (size_t)(bn + r) * K + kt + sg * 8, Bsm + (size_t)(i * 256 + w * 64) * 8);
        }
        __syncthreads();
        f16x8 av[4], bv[4];
#pragma unroll
        for (int m = 0; m < 4; m++) av[m] = *(const f16x8*)(Asm + aoff[m]);
#pragma unroll
        for (int n = 0; n < 4; n++) bv[n] = *(const f16x8*)(Bsm + boff[n]);
#pragma unroll
        for (int m = 0; m < 4; m++)
#pragma unroll
            for (int n = 0; n < 4; n++)
                acc[m][n] = __builtin_amdgcn_mfma_f32_16x16x32_f16(av[m], bv[n], acc[m][n], 0, 0, 0);
    }

#pragma unroll
    for (int m = 0; m < 4; m++) {
        int row0 = bm + wm + m * 16 + slog * 4;
        _Float16* C = (row0 < 1024) ? out0 : out1;
        int l = row0 & 1023;
#pragma unroll
        for (int n = 0; n < 4; n++) {
            int colg = bn + wn + n * 16 + r15;
            f16x4 p;
#pragma unroll
            for (int j = 0; j < 4; j++) p[j] = (_Float16)acc[m][n][j];
            *(f16x4*)(C + (size_t)colg * 1024 + l) = p;
        }
    }
}

// ---------------- big GEMM: 256x256 tile, BK=32 slab, 4-slab LDS ring, counted vmcnt ----------------
// LDS ring: 4 slabs x 32KB { A 256x32 f16 @ +0, B 256x32 f16 @ +16384 }.
// Slab row = 64 B; phys 16B slot = (logical_slot + (row>>1)) & 3  (rotate swizzle, 2-way max alias).
// Pipeline: stage slab s+3 during compute of slab s; vmcnt(8) + 1 barrier per slab.
// EPI: 1 = relu+eps -> f16 [M][N];  2 = linear -> f32 [M][N];
//      3 = split transposed (col<1024: relu+eps -> out0 [head][d][l]; else linear -> out1)
template<int EPI>
__global__ __launch_bounds__(512, 2) void gemm256(const _Float16* __restrict__ A,
                                                  const _Float16* __restrict__ Bt,
                                                  const float* __restrict__ bias,
                                                  void* __restrict__ out0,
                                                  void* __restrict__ out1,
                                                  int M, int N, int K, int nbn) {
    __shared__ __align__(16) char lds[131072];
    const int t = threadIdx.x, lane = t & 63, w = t >> 6;
    const int nwg = gridDim.x;
    const int f = (blockIdx.x & 7) * (nwg >> 3) + (blockIdx.x >> 3);   // bijective XCD swizzle
    const int bm = (f / nbn) * 256, bn = (f % nbn) * 256;
    const int wm = (w & 1) * 128, wn = (w >> 1) * 64;
    const int r15 = lane & 15, hi = lane >> 4;
    const int srow = lane >> 2, sp = lane & 3;     // staging: 16 rows/gll, 4 slots/row

    // loop-invariant ds_read byte offsets within a slab
    int aoff[8], boff[4];
#pragma unroll
    for (int m = 0; m < 8; m++) {
        int r = wm + m * 16 + r15;
        aoff[m] = r * 64 + (((hi + (r >> 1)) & 3) << 4);
    }
#pragma unroll
    for (int n = 0; n < 4; n++) {
        int r = wn + n * 16 + r15;
        boff[n] = r * 64 + (((hi + (r >> 1)) & 3) << 4);
    }

    f32x4 acc[8][4];
#pragma unroll
    for (int m = 0; m < 8; m++)
#pragma unroll
        for (int n = 0; n < 4; n++) acc[m][n] = (f32x4){0.f, 0.f, 0.f, 0.f};

    auto stage = [&](int s) {
        char* base = lds + (s & 3) * 32768;
        int kt = s * 32;
#pragma unroll
        for (int p = 0; p < 2; p++) {
            int row = w * 32 + p * 16 + srow;
            int sg = (sp - ((row >> 1) & 3)) & 3;   // pre-swizzled global slot
            GLL16(A  + (size_t)(bm + row) * K + kt + sg * 8, base + w * 2048 + p * 1024);
            GLL16(Bt + (size_t)(bn + row) * K + kt + sg * 8, base + 16384 + w * 2048 + p * 1024);
        }
    };

    const int NS = K >> 5;
    stage(0); stage(1); stage(2);
    for (int s = 0; s < NS; ++s) {
        // own slab-s loads landed; barrier makes that true for ALL waves,
        // and confirms slab s-1 reads are complete (MFMAs consumed them pre-barrier)
        if (s + 2 < NS)      asm volatile("s_waitcnt vmcnt(8)" ::: "memory");
        else if (s + 1 < NS) asm volatile("s_waitcnt vmcnt(4)" ::: "memory");
        else                 asm volatile("s_waitcnt vmcnt(0)" ::: "memory");
        asm volatile("s_barrier" ::: "memory");
        if (s + 3 < NS) stage(s + 3);               // overwrites buf of slab s-1 (reads done)
        const char* La = lds + (s & 3) * 32768;
        const char* Lb = La + 16384;
        f16x8 bv[4];
#pragma unroll
        for (int n = 0; n < 4; n++) bv[n] = *(const f16x8*)(Lb + boff[n]);
        f16x8 av[8];
#pragma unroll
        for (int m = 0; m < 8; m++) av[m] = *(const f16x8*)(La + aoff[m]);
        __builtin_amdgcn_s_setprio(1);
#pragma unroll
        for (int m = 0; m < 8; m++)
#pragma unroll
            for (int n = 0; n < 4; n++)
                acc[m][n] = __builtin_amdgcn_mfma_f32_16x16x32_f16(av[m], bv[n], acc[m][n], 0, 0, 0);
        __builtin_amdgcn_s_setprio(0);
    }

    if (EPI == 3) {
        // transposed epilogue via per-wave LDS tile [d=64][l=128] f16 (16 KB), swizzled
        asm volatile("s_barrier" ::: "memory");     // all slab reads done before LDS reuse
        char* LW = lds + w * 16384;
        const int colg0 = bn + wn;
        const bool isK = colg0 < 1024;
        _Float16* Cb = isK ? (_Float16*)out0 : (_Float16*)out1;
        const int hd = (isK ? colg0 : colg0 - 1024) >> 6;
        const int nb = bm >> 12;
        const int l0 = (bm & 4095) + wm;
#pragma unroll
        for (int m = 0; m < 8; m++)
#pragma unroll
            for (int n = 0; n < 4; n++) {
                int d = n * 16 + r15;
                float bs = bias[colg0 + d];
                f16x4 pk;
#pragma unroll
                for (int j = 0; j < 4; j++) {
                    float xv = acc[m][n][j] + bs;
                    if (isK) xv = fmaxf(xv, 0.f) + EPSF;
                    pk[j] = (_Float16)xv;
                }
                *(f16x4*)(LW + d * 256 + ((m * 32 + hi * 8) ^ ((d & 15) << 4))) = pk;
            }
        _Float16* basep = Cb + (size_t)(nb * 16 + hd) * 64 * 4096 + l0;
#pragma unroll
        for (int pass = 0; pass < 16; pass++) {
            int d = pass * 4 + hi;
            f16x8 v = *(const f16x8*)(LW + d * 256 + ((r15 * 16) ^ ((d & 15) << 4)));
            *(f16x8*)(basep + (size_t)d * 4096 + r15 * 8) = v;
        }
    } else {
#pragma unroll
        for (int m = 0; m < 8; m++) {
            int row0 = bm + wm + m * 16 + hi * 4;
#pragma unroll
            for (int n = 0; n < 4; n++) {
                int colg = bn + wn + n * 16 + r15;
                float bs = bias ? bias[colg] : 0.f;
#pragma unroll
                for (int j = 0; j < 4; j++) {
                    float xv = acc[m][n][j] + bs;
                    if (EPI == 1) {
                        xv = fmaxf(xv, 0.f) + EPSF;
                        ((_Float16*)out0)[(size_t)(row0 + j) * N + colg] = (_Float16)xv;
                    } else {
                        ((float*)out0)[(size_t)(row0 + j) * N + colg] = xv;
                    }
                }
            }
        }
    }
}

// ---------------- ksum[head][d] = sum_l KphiT[head][d][l] ----------------
__global__ __launch_bounds__(256) void ksum_kernel(const _Float16* __restrict__ KphiT,
                                                   float* __restrict__ ksum) {
    const int t = threadIdx.x, lane = t & 63, w = t >> 6;
    const int gid = blockIdx.x;          // 0..1023
    const int head = gid >> 4;
    const int d = (gid & 15) * 4 + w;
    const _Float16* src = KphiT + ((size_t)head * 64 + d) * 4096;
    float s = 0.f;
#pragma unroll
    for (int i = 0; i < 8; i++) {
        f16x8 v = *(const f16x8*)(src + (size_t)(i * 64 + lane) * 8);
#pragma unroll
        for (int j = 0; j < 8; j++) s += (float)v[j];
    }
#pragma unroll
    for (int o = 32; o; o >>= 1) s += __shfl_xor(s, o, 64);
    if (lane == 0) ksum[(size_t)head * 64 + d] = s;
}

// ---------------- kv partials ----------------
__global__ __launch_bounds__(256) void kvt_kernel(const _Float16* __restrict__ Vt,
                                                  const _Float16* __restrict__ KphiT,
                                                  float* __restrict__ kvpart) {
    const int t = threadIdx.x, lane = t & 63, w = t >> 6;
    const int head = blockIdx.y;
    const int l0 = blockIdx.x * 1024;
    __shared__ __align__(16) _Float16 As[64 * 128];
    __shared__ __align__(16) _Float16 Bs[64 * 128];
    const int r15 = lane & 15, slog = lane >> 4;
    f32x4 acc[4][4];
#pragma unroll
    for (int m = 0; m < 4; m++)
#pragma unroll
        for (int n = 0; n < 4; n++) acc[m][n] = (f32x4){0.f, 0.f, 0.f, 0.f};

    for (int it = 0; it < 8; it++) {
        __syncthreads();
        int lbase = l0 + it * 128;
#pragma unroll
        for (int i = 0; i < 4; i++) {
            int seg = i * 256 + w * 64 + lane;
            int r = seg >> 4, sp2 = seg & 15;
            int sg = sp2 ^ (r & 15);
            GLL16(Vt    + ((size_t)head * 64 + r) * 4096 + lbase + sg * 8, As + (size_t)(i * 256 + w * 64) * 8);
            GLL16(KphiT + ((size_t)head * 64 + r) * 4096 + lbase + sg * 8, Bs + (size_t)(i * 256 + w * 64) * 8);
        }
        __syncthreads();
        f16x8 av[4], bv[4];
#pragma unroll
        for (int m = 0; m < 4; m++) {
            int r = m * 16 + r15;
            int s2 = w * 4 + slog;
            int ph = s2 ^ (r & 15);
            av[m] = *(const f16x8*)(As + r * 128 + ph * 8);
            bv[m] = *(const f16x8*)(Bs + r * 128 + ph * 8);
        }
#pragma unroll
        for (int m = 0; m < 4; m++)
#pragma unroll
            for (int n = 0; n < 4; n++)
                acc[m][n] = __builtin_amdgcn_mfma_f32_16x16x32_f16(av[m], bv[n], acc[m][n], 0, 0, 0);
    }
    float* red = (float*)As;
    for (int ww = 0; ww < 4; ww++) {
        __syncthreads();
        if (w == ww) {
#pragma unroll
            for (int m = 0; m < 4; m++)
#pragma unroll
                for (int n = 0; n < 4; n++)
#pragma unroll
                    for (int j = 0; j < 4; j++) {
                        int row = m * 16 + slog * 4 + j, col = n * 16 + r15;
                        if (ww == 0) red[row * 64 + col] = acc[m][n][j];
                        else         red[row * 64 + col] += acc[m][n][j];
                    }
        }
    }
    __syncthreads();
    float* outp = kvpart + ((size_t)head * 4 + blockIdx.x) * 4096;
#pragma unroll
    for (int i = 0; i < 16; i++) { int idx = i * 256 + t; outp[idx] = red[idx]; }
}

__global__ __launch_bounds__(256) void kvreduce(const float* __restrict__ kvpart,
                                                float* __restrict__ kvT) {
    int head = blockIdx.x, t = threadIdx.x;
#pragma unroll
    for (int i = 0; i < 16; i++) {
        int idx = i * 256 + t;
        float s = 0.f;
#pragma unroll
        for (int c = 0; c < 4; c++) s += kvpart[((size_t)head * 4 + c) * 4096 + idx];
        kvT[(size_t)head * 4096 + idx] = s;
    }
}

// ---------------- numerator GEMM + denominator + divide -> U (f16) ----------------
__global__ __launch_bounds__(256) void numdiv_kernel(const _Float16* __restrict__ Qphi,
                                                     const float* __restrict__ kvT,
                                                     const float* __restrict__ ksum,
                                                     _Float16* __restrict__ U) {
    const int t = threadIdx.x, lane = t & 63, w = t >> 6;
    const int h = blockIdx.y;
    const int m0 = blockIdx.x * 256;
    const int nb = m0 >> 12;
    const int head = nb * 16 + h;
    __shared__ __align__(16) _Float16 Qs[256 * 64];
    __shared__ __align__(16) _Float16 Bs[64 * 64];
    __shared__ float ksl[64];

#pragma unroll
    for (int i = 0; i < 8; i++) {
        int seg = i * 256 + w * 64 + lane;
        int r = seg >> 3, sp = seg & 7;
        int sg = sp ^ (r & 7);
        GLL16(Qphi + (size_t)(m0 + r) * 1024 + h * 64 + sg * 8, Qs + (size_t)(i * 256 + w * 64) * 8);
    }
#pragma unroll
    for (int i = 0; i < 2; i++) {
        int sidx = i * 256 + t;
        int r = sidx >> 3, p = sidx & 7;
        int sg = p ^ (r & 7);
        const float4* src = (const float4*)(kvT + (size_t)head * 4096 + r * 64 + sg * 8);
        float4 v0 = src[0], v1 = src[1];
        f16x8 o;
        o[0] = (_Float16)v0.x; o[1] = (_Float16)v0.y; o[2] = (_Float16)v0.z; o[3] = (_Float16)v0.w;
        o[4] = (_Float16)v1.x; o[5] = (_Float16)v1.y; o[6] = (_Float16)v1.z; o[7] = (_Float16)v1.w;
        *(f16x8*)(Bs + sidx * 8) = o;
    }
    if (t < 64) ksl[t] = ksum[(size_t)head * 64 + t];
    __syncthreads();

    const int r15 = lane & 15, slog = lane >> 4;
    f32x4 acc[4][4];
#pragma unroll
    for (int m = 0; m < 4; m++)
#pragma unroll
        for (int n = 0; n < 4; n++) acc[m][n] = (f32x4){0.f, 0.f, 0.f, 0.f};
    float dp[4] = {0.f, 0.f, 0.f, 0.f};

#pragma unroll
    for (int kk = 0; kk < 2; kk++) {
        float ks[8];
#pragma unroll
        for (int j = 0; j < 8; j++) ks[j] = ksl[kk * 32 + slog * 8 + j];
        f16x8 av[4], bv[4];
#pragma unroll
        for (int m = 0; m < 4; m++) {
            int r = w * 64 + m * 16 + r15;
            int ph = (kk * 4 + slog) ^ (r & 7);
            av[m] = *(const f16x8*)(Qs + r * 64 + ph * 8);
        }
#pragma unroll
        for (int n = 0; n < 4; n++) {
            int r = n * 16 + r15;
            int ph = (kk * 4 + slog) ^ (r & 7);
            bv[n] = *(const f16x8*)(Bs + r * 64 + ph * 8);
        }
#pragma unroll
        for (int m = 0; m < 4; m++)
#pragma unroll
            for (int j = 0; j < 8; j++) dp[m] += (float)av[m][j] * ks[j];
#pragma unroll
        for (int m = 0; m < 4; m++)
#pragma unroll
            for (int n = 0; n < 4; n++)
                acc[m][n] = __builtin_amdgcn_mfma_f32_16x16x32_f16(av[m], bv[n], acc[m][n], 0, 0, 0);
    }
#pragma unroll
    for (int m = 0; m < 4; m++) {
        dp[m] += __shfl_xor(dp[m], 16, 64);
        dp[m] += __shfl_xor(dp[m], 32, 64);
    }
#pragma unroll
    for (int m = 0; m < 4; m++) {
#pragma unroll
        for (int j = 0; j < 4; j++) {
            float den = __shfl(dp[m], slog * 4 + j, 64);
            float inv = __builtin_amdgcn_rcpf(den);
            int row = m0 + w * 64 + m * 16 + slog * 4 + j;
#pragma unroll
            for (int n = 0; n < 4; n++)
                U[(size_t)row * 1024 + h * 64 + n * 16 + r15] = (_Float16)(acc[m][n][j] * inv);
        }
    }
}

// ------------------------------------------------------------------------------------
extern "C" void kernel_launch(void* const* d_in, const int* in_sizes, int n_in,
                              void* d_out, int out_size, void* d_ws, size_t ws_size,
                              hipStream_t stream) {
    (void)in_sizes; (void)n_in; (void)out_size; (void)ws_size;
    const float* x     = (const float*)d_in[0];
    const float* y     = (const float*)d_in[1];
    const float* WQ    = (const float*)d_in[2];
    const float* bQ    = (const float*)d_in[3];
    const float* WK    = (const float*)d_in[4];
    const float* bK    = (const float*)d_in[5];
    const float* WV    = (const float*)d_in[6];
    const float* bV    = (const float*)d_in[7];
    const float* WO    = (const float*)d_in[8];
    const float* bO    = (const float*)d_in[9];
    const float* omega = (const float*)d_in[10];

    char* ws = (char*)d_ws;
    size_t off = 0;
    auto alloc = [&](size_t bytes) { void* p = ws + off; off += (bytes + 255) & ~(size_t)255; return p; };
    const size_t BIG = (size_t)16384 * 1024 * 2;    // 32 MiB f16
    _Float16* xb    = (_Float16*)alloc(BIG);        // reused for U later
    _Float16* yb    = (_Float16*)alloc(BIG);
    _Float16* WQKb  = (_Float16*)alloc((size_t)2048 * 1024 * 2);  // stacked WQ;WK f16
    _Float16* obdT  = (_Float16*)alloc(1024 * 1024 * 2);
    _Float16* Wqt   = (_Float16*)alloc(1024 * 1024 * 2);
    _Float16* Wkvt  = (_Float16*)alloc((size_t)2048 * 1024 * 2);  // rows 0-1023: K-fold, 1024-2047: V^T
    _Float16* Wot   = (_Float16*)alloc(1024 * 1024 * 2);
    float*    bQf   = (float*)alloc(1024 * 4);
    float*    bkv   = (float*)alloc(2048 * 4);
    _Float16* Qphi  = (_Float16*)alloc(BIG);
    _Float16* KphiT = (_Float16*)alloc(BIG);
    _Float16* Vt    = (_Float16*)alloc(BIG);
    float*    kvpart= (float*)alloc((size_t)256 * 4096 * 4);
    float*    kvT   = (float*)alloc((size_t)64 * 4096 * 4);
    float*    ksum  = (float*)alloc((size_t)64 * 64 * 4);
    _Float16* U     = xb;  // alias: xb dead after Qphi GEMM

    // 1. precision converts
    cvt_f16<<<2048, 256, 0, stream>>>(x, xb, 16384 * 1024 / 8);
    cvt_f16<<<2048, 256, 0, stream>>>(y, yb, 16384 * 1024 / 8);
    cvt_f16<<<512, 256, 0, stream>>>(WQ, WQKb, 1024 * 1024 / 8);
    cvt_f16<<<512, 256, 0, stream>>>(WK, WQKb + (size_t)1024 * 1024, 1024 * 1024 / 8);
    // 2. omega block-diag (transposed) + weight transposes + bias folds
    build_obdT<<<4096, 256, 0, stream>>>(omega, obdT);
    transpose_cvt<<<dim3(16, 16), 256, 0, stream>>>(WV, Wkvt + (size_t)1024 * 1024);
    transpose_cvt<<<dim3(16, 16), 256, 0, stream>>>(WO, Wot);
    fold_bias<<<4, 256, 0, stream>>>(bQ, omega, bQf);
    fold_bias<<<4, 256, 0, stream>>>(bK, omega, bkv);
    copy_f32<<<4, 256, 0, stream>>>(bV, bkv + 1024, 1024);
    // 3. fold omega into WQ/WK (single M=2048 GEMM, outputs transposed into Bt layout)
    gemm_fold<<<dim3(8, 16), 256, 0, stream>>>(WQKb, obdT, Wqt, Wkvt);
    // 4. projections: Q (relu+eps), K|V merged (K relu+eps transposed, V linear transposed)
    gemm256<1><<<256, 512, 0, stream>>>(xb, Wqt, bQf, Qphi, nullptr, 16384, 1024, 1024, 4);
    gemm256<3><<<512, 512, 0, stream>>>(yb, Wkvt, bkv, KphiT, Vt, 16384, 2048, 1024, 8);
    // 5. per-head reductions
    ksum_kernel<<<1024, 256, 0, stream>>>(KphiT, ksum);
    kvt_kernel<<<dim3(4, 64), 256, 0, stream>>>(Vt, KphiT, kvpart);
    kvreduce<<<64, 256, 0, stream>>>(kvpart, kvT);
    // 6. numerator / denominator / divide
    numdiv_kernel<<<dim3(64, 16), 256, 0, stream>>>(Qphi, kvT, ksum, U);
    // 7. output projection
    gemm256<2><<<256, 512, 0, stream>>>(U, Wot, bO, d_out, nullptr, 16384, 1024, 1024, 4);
}